// Round 9
// baseline (388.216 us; speedup 1.0000x reference)
//
#include <hip/hip_runtime.h>
#include <hip/hip_bf16.h>
#include <cstdint>

#define D_IN 128
#define DK 32
#define NH 8
#define HD 256   // NH*DK
#define KVW 512  // K row | V row interleaved per node

typedef __attribute__((ext_vector_type(8))) short short8;
typedef __attribute__((ext_vector_type(4))) float f32x4;

__device__ inline float bf2f(unsigned short u) {
  union { unsigned int i; float f; } c;
  c.i = ((unsigned int)u) << 16;
  return c.f;
}
__device__ inline float u2f(unsigned int u) {
  union { unsigned int i; float f; } c; c.i = u; return c.f;
}
__device__ inline short f2bf(float f) {
  union { float f; unsigned int i; } c; c.f = f;
  unsigned int u = c.i;
  u = u + 0x7FFFu + ((u >> 16) & 1u);  // RNE
  return (short)(u >> 16);
}

// ---------- K0: prep_w (blocks 0-47) + zero cnt (blocks 48+) ----------
__global__ __launch_bounds__(256) void prep_w_zero_kernel(
    const float* __restrict__ WQ, const float* __restrict__ WK,
    const float* __restrict__ WV, short8* __restrict__ Bbuf,
    int* __restrict__ cnt, int n_node) {
  if (blockIdx.x < 48) {
    int ct = blockIdx.x;
    int t = threadIdx.x;
    int kt = t >> 6, L = t & 63;
    int col = ct * 16 + (L & 15);
    int type = col >> 8;
    const float* W = (type == 0) ? WQ : (type == 1) ? WK : WV;
    int head = (col & 255) >> 5;
    int kk = col & 31;
    int k0 = kt * 32 + ((L >> 4) << 3);
    short8 o;
    #pragma unroll
    for (int r = 0; r < 8; r++)
      o[r] = f2bf(W[head * (D_IN * DK) + (k0 + r) * DK + kk]);
    Bbuf[(size_t)(ct * 4 + kt) * 64 + L] = o;
  } else {
    int i = (blockIdx.x - 48) * 256 + threadIdx.x;
    if (i < n_node) cnt[i] = 0;
  }
}

// ---------- K1: MFMA GEMM (blocks < nt_total) + rank (blocks >= nt_total) ----------
// The two halves are fully independent: gemm touches h/Bbuf/Q/KV, rank
// touches row/cnt/rank. Overlapping them hides gemm's store traffic under
// rank's atomic latency.
__global__ __launch_bounds__(256) void gemm_rank_kernel(
    const float* __restrict__ h, const short8* __restrict__ Bbuf,
    __hip_bfloat16* __restrict__ Q, __hip_bfloat16* __restrict__ KV,
    int nt_total, const int* __restrict__ row, int n_edge,
    int* __restrict__ cnt, int* __restrict__ rank) {
  if (blockIdx.x >= (unsigned)nt_total) {
    int i = (blockIdx.x - nt_total) * 256 + threadIdx.x;
    if (i < n_edge) rank[i] = atomicAdd(&cnt[row[i]], 1);
    return;
  }
  __shared__ float hs[16][132];   // +4 pad: conflict-free fragment reads
  __shared__ short lds[16][768];  // Q 0-255 | K 256-511 | V 512-767
  int nt = blockIdx.x;
  int t = threadIdx.x;
  {
    const float4* h4 = (const float4*)(h + (size_t)nt * 16 * 128);
    float4 v0 = h4[t * 2], v1 = h4[t * 2 + 1];
    int node = t >> 4, dim = (t & 15) * 8;
    hs[node][dim + 0] = v0.x; hs[node][dim + 1] = v0.y;
    hs[node][dim + 2] = v0.z; hs[node][dim + 3] = v0.w;
    hs[node][dim + 4] = v1.x; hs[node][dim + 5] = v1.y;
    hs[node][dim + 6] = v1.z; hs[node][dim + 7] = v1.w;
  }
  __syncthreads();
  int w = t >> 6;
  int L = t & 63;
  int arow = L & 15, k0base = ((L >> 4) << 3);
  short8 afrag[4];
  #pragma unroll
  for (int kt = 0; kt < 4; kt++) {
    #pragma unroll
    for (int r = 0; r < 8; r++)
      afrag[kt][r] = f2bf(hs[arow][kt * 32 + k0base + r]);
  }
  f32x4 acc[12];
  #pragma unroll
  for (int c = 0; c < 12; c++) acc[c] = (f32x4){0.f, 0.f, 0.f, 0.f};
  #pragma unroll
  for (int kt = 0; kt < 4; kt++) {
    #pragma unroll
    for (int c = 0; c < 12; c++) {
      short8 b = Bbuf[(size_t)((w * 12 + c) * 4 + kt) * 64 + L];
      acc[c] = __builtin_amdgcn_mfma_f32_16x16x32_bf16(afrag[kt], b, acc[c], 0, 0, 0);
    }
  }
  int row0 = (L >> 4) << 2;
  int col0 = w * 192 + (L & 15);
  #pragma unroll
  for (int c = 0; c < 12; c++) {
    #pragma unroll
    for (int r = 0; r < 4; r++)
      lds[row0 + r][col0 + c * 16] = f2bf(acc[c][r]);
  }
  __syncthreads();
  // Q out: 512 16B-units, fully coalesced
  #pragma unroll
  for (int j = 0; j < 2; j++) {
    int u = t + j * 256;
    int r2 = u >> 5, uc = u & 31;
    float4 vdat = *(const float4*)&lds[r2][uc * 8];
    *(float4*)(Q + (size_t)(nt * 16 + r2) * HD + uc * 8) = vdat;
  }
  // KV out: 1024 16B-units
  #pragma unroll
  for (int j = 0; j < 4; j++) {
    int u = t + j * 256;
    int r2 = u >> 6, uc = u & 63;
    float4 vdat = *(const float4*)&lds[r2][256 + uc * 8];
    *(float4*)(KV + (size_t)(nt * 16 + r2) * KVW + uc * 8) = vdat;
  }
}

// ---------------- scans ----------------
__global__ __launch_bounds__(256) void scan1_kernel(
    const int* __restrict__ cnt, int n, int* __restrict__ exc,
    int* __restrict__ bsum) {
  __shared__ int s[256];
  int gid = blockIdx.x * 256 + threadIdx.x;
  int v = (gid < n) ? cnt[gid] : 0;
  s[threadIdx.x] = v;
  __syncthreads();
  #pragma unroll
  for (int off = 1; off < 256; off <<= 1) {
    int t = (threadIdx.x >= off) ? s[threadIdx.x - off] : 0;
    __syncthreads();
    s[threadIdx.x] += t;
    __syncthreads();
  }
  if (gid < n) exc[gid] = s[threadIdx.x] - v;
  if (threadIdx.x == 255) bsum[blockIdx.x] = s[255];
}

__global__ __launch_bounds__(256) void scan2_kernel(int* __restrict__ bsum,
                                                    int nb) {
  __shared__ int s[256];
  int v = (threadIdx.x < nb) ? bsum[threadIdx.x] : 0;
  s[threadIdx.x] = v;
  __syncthreads();
  #pragma unroll
  for (int off = 1; off < 256; off <<= 1) {
    int t = (threadIdx.x >= off) ? s[threadIdx.x - off] : 0;
    __syncthreads();
    s[threadIdx.x] += t;
    __syncthreads();
  }
  if (threadIdx.x < nb) bsum[threadIdx.x] = s[threadIdx.x] - v;
}

__global__ __launch_bounds__(256) void scan3_kernel(
    int* __restrict__ exc, const int* __restrict__ bsum, int n, int n_edge) {
  int gid = blockIdx.x * 256 + threadIdx.x;
  if (gid < n) exc[gid] = exc[gid] + bsum[blockIdx.x];
  if (gid == 0) exc[n] = n_edge;
}

__global__ void scatter_kernel(const int* __restrict__ row,
                               const int* __restrict__ col,
                               const int* __restrict__ rank, int n_edge,
                               const int* __restrict__ offsets,
                               int* __restrict__ col_sorted) {
  int i = blockIdx.x * blockDim.x + threadIdx.x;
  if (i < n_edge) col_sorted[offsets[row[i]] + rank[i]] = col[i];
}

// ---------------- Attention: one wave per node, ONE 1KB load per edge ----------------
#define AT_PROCESS(r)                                                        \
  {                                                                          \
    float x0 = u2f(r.x << 16), x1 = u2f(r.x & 0xFFFF0000u);                  \
    float x2 = u2f(r.y << 16), x3 = u2f(r.y & 0xFFFF0000u);                  \
    float x4 = u2f(r.z << 16), x5 = u2f(r.z & 0xFFFF0000u);                  \
    float x6 = u2f(r.w << 16), x7 = u2f(r.w & 0xFFFF0000u);                  \
    float d = x0 * qf0;                                                      \
    d = fmaf(x1, qf1, d); d = fmaf(x2, qf2, d); d = fmaf(x3, qf3, d);        \
    d = fmaf(x4, qf4, d); d = fmaf(x5, qf5, d); d = fmaf(x6, qf6, d);        \
    d = fmaf(x7, qf7, d);                                                    \
    d += __shfl_xor(d, 1);                                                   \
    d += __shfl_xor(d, 2);                                                   \
    float lg = __shfl(d, sub);                                               \
    if (__any(lg - m > 8.0f)) {                                              \
      float nm = fmaxf(m, lg);                                               \
      float sc = __expf(m - nm);                                             \
      denom *= sc;                                                           \
      a0 *= sc; a1 *= sc; a2 *= sc; a3 *= sc;                                \
      a4 *= sc; a5 *= sc; a6 *= sc; a7 *= sc;                                \
      m = nm;                                                                \
    }                                                                        \
    float p = __expf(lg - m);                                                \
    denom += p;                                                              \
    a0 = fmaf(p, x0, a0); a1 = fmaf(p, x1, a1);                              \
    a2 = fmaf(p, x2, a2); a3 = fmaf(p, x3, a3);                              \
    a4 = fmaf(p, x4, a4); a5 = fmaf(p, x5, a5);                              \
    a6 = fmaf(p, x6, a6); a7 = fmaf(p, x7, a7);                              \
  }

__global__ __launch_bounds__(256) void attn_kernel(
    const __hip_bfloat16* __restrict__ Q, const __hip_bfloat16* __restrict__ KV,
    const int* __restrict__ offsets, const int* __restrict__ col_sorted,
    float* __restrict__ out, int n_node) {
  int wave = threadIdx.x >> 6;
  int lane = threadIdx.x & 63;
  int sub = lane & 31;
  int node = blockIdx.x * 4 + wave;
  if (node >= n_node) return;
  int start = offsets[node], end = offsets[node + 1];

  const float QS = 0.17677669529663687f;
  float qf0, qf1, qf2, qf3, qf4, qf5, qf6, qf7;
  {
    uint4 qr = *(const uint4*)(Q + (size_t)node * HD + sub * 8);
    qf0 = u2f(qr.x << 16) * QS; qf1 = u2f(qr.x & 0xFFFF0000u) * QS;
    qf2 = u2f(qr.y << 16) * QS; qf3 = u2f(qr.y & 0xFFFF0000u) * QS;
    qf4 = u2f(qr.z << 16) * QS; qf5 = u2f(qr.z & 0xFFFF0000u) * QS;
    qf6 = u2f(qr.w << 16) * QS; qf7 = u2f(qr.w & 0xFFFF0000u) * QS;
  }
  float m = -INFINITY, denom = 0.f;
  float a0 = 0.f, a1 = 0.f, a2 = 0.f, a3 = 0.f;
  float a4 = 0.f, a5 = 0.f, a6 = 0.f, a7 = 0.f;

  const char* kvbase = (const char*)KV + lane * 16;
  int e = start;
  for (; e + 8 <= end; e += 8) {
    int c0 = col_sorted[e],     c1 = col_sorted[e + 1];
    int c2 = col_sorted[e + 2], c3 = col_sorted[e + 3];
    int c4 = col_sorted[e + 4], c5 = col_sorted[e + 5];
    int c6 = col_sorted[e + 6], c7 = col_sorted[e + 7];
    uint4 r0 = *(const uint4*)(kvbase + (size_t)c0 * 1024);
    uint4 r1 = *(const uint4*)(kvbase + (size_t)c1 * 1024);
    uint4 r2 = *(const uint4*)(kvbase + (size_t)c2 * 1024);
    uint4 r3 = *(const uint4*)(kvbase + (size_t)c3 * 1024);
    uint4 r4 = *(const uint4*)(kvbase + (size_t)c4 * 1024);
    uint4 r5 = *(const uint4*)(kvbase + (size_t)c5 * 1024);
    uint4 r6 = *(const uint4*)(kvbase + (size_t)c6 * 1024);
    uint4 r7 = *(const uint4*)(kvbase + (size_t)c7 * 1024);
    AT_PROCESS(r0); AT_PROCESS(r1); AT_PROCESS(r2); AT_PROCESS(r3);
    AT_PROCESS(r4); AT_PROCESS(r5); AT_PROCESS(r6); AT_PROCESS(r7);
  }
  for (; e + 4 <= end; e += 4) {
    int c0 = col_sorted[e],     c1 = col_sorted[e + 1];
    int c2 = col_sorted[e + 2], c3 = col_sorted[e + 3];
    uint4 r0 = *(const uint4*)(kvbase + (size_t)c0 * 1024);
    uint4 r1 = *(const uint4*)(kvbase + (size_t)c1 * 1024);
    uint4 r2 = *(const uint4*)(kvbase + (size_t)c2 * 1024);
    uint4 r3 = *(const uint4*)(kvbase + (size_t)c3 * 1024);
    AT_PROCESS(r0); AT_PROCESS(r1); AT_PROCESS(r2); AT_PROCESS(r3);
  }
  for (; e < end; e++) {
    int c = col_sorted[e];
    uint4 r = *(const uint4*)(kvbase + (size_t)c * 1024);
    AT_PROCESS(r);
  }

  float inv = (end > start) ? 1.f / denom : 0.f;
  if (lane >= 32) {
    float* op = out + (size_t)node * HD + sub * 8;
    float4 o0 = make_float4(a0 * inv, a1 * inv, a2 * inv, a3 * inv);
    float4 o1 = make_float4(a4 * inv, a5 * inv, a6 * inv, a7 * inv);
    *(float4*)op = o0;
    *(float4*)(op + 4) = o1;
  }
}

extern "C" void kernel_launch(void* const* d_in, const int* in_sizes, int n_in,
                              void* d_out, int out_size, void* d_ws,
                              size_t ws_size, hipStream_t stream) {
  const float* h = (const float*)d_in[0];
  const int* edge = (const int*)d_in[1];
  const float* WQ = (const float*)d_in[2];
  const float* WK = (const float*)d_in[3];
  const float* WV = (const float*)d_in[4];
  float* out = (float*)d_out;

  int n_node = in_sizes[0] / D_IN;
  int n_edge = in_sizes[1] / 2;
  const int* row = edge;
  const int* col = edge + n_edge;

  char* ws = (char*)d_ws;
  size_t off = 0;
  auto alloc = [&](size_t bytes) {
    void* p = ws + off;
    off += (bytes + 255) & ~(size_t)255;
    return p;
  };
  int nt_total = (n_node + 15) / 16;  // 3125 (50000 = 3125*16 exactly)
  __hip_bfloat16* Q = (__hip_bfloat16*)alloc((size_t)nt_total * 16 * HD * 2);
  __hip_bfloat16* KV = (__hip_bfloat16*)alloc((size_t)nt_total * 16 * KVW * 2);
  short8* Bbuf = (short8*)alloc((size_t)48 * 4 * 64 * 16);
  int* col_sorted = (int*)alloc((size_t)n_edge * 4);
  int* rank = (int*)alloc((size_t)n_edge * 4);
  int* cnt = (int*)alloc((size_t)n_node * 4);
  int* offsets = (int*)alloc((size_t)(n_node + 1) * 4);
  int* bsum = (int*)alloc(256 * 4);

  int nb = (n_node + 255) / 256;    // 196
  int nb_e = (n_edge + 255) / 256;  // 6250

  // K0: prep_w + zero cnt (independent)
  prep_w_zero_kernel<<<48 + nb, 256, 0, stream>>>(WQ, WK, WV, Bbuf, cnt,
                                                  n_node);
  // K1: gemm ∥ rank (independent halves, overlap in one dispatch)
  gemm_rank_kernel<<<nt_total + nb_e, 256, 0, stream>>>(
      h, Bbuf, Q, KV, nt_total, row, n_edge, cnt, rank);

  scan1_kernel<<<nb, 256, 0, stream>>>(cnt, n_node, offsets, bsum);
  scan2_kernel<<<1, 256, 0, stream>>>(bsum, nb);
  scan3_kernel<<<nb, 256, 0, stream>>>(offsets, bsum, n_node, n_edge);

  scatter_kernel<<<nb_e, 256, 0, stream>>>(row, col, rank, n_edge, offsets,
                                           col_sorted);

  attn_kernel<<<(n_node + 3) / 4, 256, 0, stream>>>(Q, KV, offsets, col_sorted,
                                                    out, n_node);
}

// Round 10
// 378.930 us; speedup vs baseline: 1.0245x; 1.0245x over previous
//
#include <hip/hip_runtime.h>
#include <hip/hip_bf16.h>
#include <cstdint>

#define D_IN 128
#define DK 32
#define NH 8
#define HD 256   // NH*DK
#define KVW 512  // K row | V row interleaved per node

typedef __attribute__((ext_vector_type(8))) short short8;
typedef __attribute__((ext_vector_type(4))) float f32x4;

__device__ inline float u2f(unsigned int u) {
  union { unsigned int i; float f; } c; c.i = u; return c.f;
}
__device__ inline short f2bf(float f) {
  union { float f; unsigned int i; } c; c.f = f;
  unsigned int u = c.i;
  u = u + 0x7FFFu + ((u >> 16) & 1u);  // RNE
  return (short)(u >> 16);
}
__device__ inline void gll16(const void* gsrc, void* ldst) {
  __builtin_amdgcn_global_load_lds(
      (const __attribute__((address_space(1))) unsigned int*)gsrc,
      (__attribute__((address_space(3))) unsigned int*)ldst, 16, 0, 0);
}

// ---------- prep B: Wcat[128][768] -> bf16 MFMA B-fragments ----------
__global__ __launch_bounds__(256) void prep_w_kernel(
    const float* __restrict__ WQ, const float* __restrict__ WK,
    const float* __restrict__ WV, short8* __restrict__ Bbuf) {
  int ct = blockIdx.x;  // 0..47
  int t = threadIdx.x;
  int kt = t >> 6, L = t & 63;
  int col = ct * 16 + (L & 15);
  int type = col >> 8;
  const float* W = (type == 0) ? WQ : (type == 1) ? WK : WV;
  int head = (col & 255) >> 5;
  int kk = col & 31;
  int k0 = kt * 32 + ((L >> 4) << 3);
  short8 o;
  #pragma unroll
  for (int r = 0; r < 8; r++)
    o[r] = f2bf(W[head * (D_IN * DK) + (k0 + r) * DK + kk]);
  Bbuf[(size_t)(ct * 4 + kt) * 64 + L] = o;
}

// ---------- MFMA GEMM: one block per 16-node tile; writes Q + interleaved KV ----------
__global__ __launch_bounds__(256) void gemm_qkv_kernel(
    const float* __restrict__ h, const short8* __restrict__ Bbuf,
    __hip_bfloat16* __restrict__ Q, __hip_bfloat16* __restrict__ KV,
    int nt_total) {
  __shared__ float hs[16][132];
  __shared__ short lds[16][768];  // Q 0-255 | K 256-511 | V 512-767
  int nt = blockIdx.x;
  int t = threadIdx.x;
  {
    const float4* h4 = (const float4*)(h + (size_t)nt * 16 * 128);
    float4 v0 = h4[t * 2], v1 = h4[t * 2 + 1];
    int node = t >> 4, dim = (t & 15) * 8;
    hs[node][dim + 0] = v0.x; hs[node][dim + 1] = v0.y;
    hs[node][dim + 2] = v0.z; hs[node][dim + 3] = v0.w;
    hs[node][dim + 4] = v1.x; hs[node][dim + 5] = v1.y;
    hs[node][dim + 6] = v1.z; hs[node][dim + 7] = v1.w;
  }
  __syncthreads();
  int w = t >> 6;
  int L = t & 63;
  int arow = L & 15, k0base = ((L >> 4) << 3);
  short8 afrag[4];
  #pragma unroll
  for (int kt = 0; kt < 4; kt++) {
    #pragma unroll
    for (int r = 0; r < 8; r++)
      afrag[kt][r] = f2bf(hs[arow][kt * 32 + k0base + r]);
  }
  f32x4 acc[12];
  #pragma unroll
  for (int c = 0; c < 12; c++) acc[c] = (f32x4){0.f, 0.f, 0.f, 0.f};
  #pragma unroll
  for (int kt = 0; kt < 4; kt++) {
    #pragma unroll
    for (int c = 0; c < 12; c++) {
      short8 b = Bbuf[(size_t)((w * 12 + c) * 4 + kt) * 64 + L];
      acc[c] = __builtin_amdgcn_mfma_f32_16x16x32_bf16(afrag[kt], b, acc[c], 0, 0, 0);
    }
  }
  int row0 = (L >> 4) << 2;
  int col0 = w * 192 + (L & 15);
  #pragma unroll
  for (int c = 0; c < 12; c++) {
    #pragma unroll
    for (int r = 0; r < 4; r++)
      lds[row0 + r][col0 + c * 16] = f2bf(acc[c][r]);
  }
  __syncthreads();
  #pragma unroll
  for (int j = 0; j < 2; j++) {
    int u = t + j * 256;
    int r2 = u >> 5, uc = u & 31;
    float4 vdat = *(const float4*)&lds[r2][uc * 8];
    *(float4*)(Q + (size_t)(nt * 16 + r2) * HD + uc * 8) = vdat;
  }
  #pragma unroll
  for (int j = 0; j < 4; j++) {
    int u = t + j * 256;
    int r2 = u >> 6, uc = u & 63;
    float4 vdat = *(const float4*)&lds[r2][256 + uc * 8];
    *(float4*)(KV + (size_t)(nt * 16 + r2) * KVW + uc * 8) = vdat;
  }
}

// ---------------- CSR build ----------------
__global__ void rank_kernel(const int* __restrict__ row, int n_edge,
                            int* __restrict__ cnt, int* __restrict__ rank) {
  int i = blockIdx.x * blockDim.x + threadIdx.x;
  if (i < n_edge) rank[i] = atomicAdd(&cnt[row[i]], 1);
}

__global__ __launch_bounds__(256) void scan1_kernel(
    const int* __restrict__ cnt, int n, int* __restrict__ exc,
    int* __restrict__ bsum) {
  __shared__ int s[256];
  int gid = blockIdx.x * 256 + threadIdx.x;
  int v = (gid < n) ? cnt[gid] : 0;
  s[threadIdx.x] = v;
  __syncthreads();
  #pragma unroll
  for (int off = 1; off < 256; off <<= 1) {
    int t = (threadIdx.x >= off) ? s[threadIdx.x - off] : 0;
    __syncthreads();
    s[threadIdx.x] += t;
    __syncthreads();
  }
  if (gid < n) exc[gid] = s[threadIdx.x] - v;
  if (threadIdx.x == 255) bsum[blockIdx.x] = s[255];
}

__global__ __launch_bounds__(256) void scan2_kernel(int* __restrict__ bsum,
                                                    int nb) {
  __shared__ int s[256];
  int v = (threadIdx.x < nb) ? bsum[threadIdx.x] : 0;
  s[threadIdx.x] = v;
  __syncthreads();
  #pragma unroll
  for (int off = 1; off < 256; off <<= 1) {
    int t = (threadIdx.x >= off) ? s[threadIdx.x - off] : 0;
    __syncthreads();
    s[threadIdx.x] += t;
    __syncthreads();
  }
  if (threadIdx.x < nb) bsum[threadIdx.x] = s[threadIdx.x] - v;
}

__global__ __launch_bounds__(256) void scan3_kernel(
    int* __restrict__ exc, const int* __restrict__ bsum, int n, int n_edge) {
  int gid = blockIdx.x * 256 + threadIdx.x;
  if (gid < n) exc[gid] = exc[gid] + bsum[blockIdx.x];
  if (gid == 0) exc[n] = n_edge;
}

__global__ void scatter_kernel(const int* __restrict__ row,
                               const int* __restrict__ col,
                               const int* __restrict__ rank, int n_edge,
                               const int* __restrict__ offsets,
                               int* __restrict__ col_sorted) {
  int i = blockIdx.x * blockDim.x + threadIdx.x;
  if (i < n_edge) col_sorted[offsets[row[i]] + rank[i]] = col[i];
}

// ---------------- Attention: one wave/node, async LDS pipeline ----------------
// Double-buffered 2x4-edge LDS slots per wave (8KB). global_load_lds width=16
// streams each 1KB KV row to LDS with ZERO VGPR cost; counted vmcnt(4) keeps
// 8 edge-loads in flight. Per-wave vmcnt -> no barriers, no cross-wave sync.
#define AT_PROCESS(r, valid)                                                 \
  {                                                                          \
    float x0 = u2f(r.x << 16), x1 = u2f(r.x & 0xFFFF0000u);                  \
    float x2 = u2f(r.y << 16), x3 = u2f(r.y & 0xFFFF0000u);                  \
    float x4 = u2f(r.z << 16), x5 = u2f(r.z & 0xFFFF0000u);                  \
    float x6 = u2f(r.w << 16), x7 = u2f(r.w & 0xFFFF0000u);                  \
    float d = x0 * qf0;                                                      \
    d = fmaf(x1, qf1, d); d = fmaf(x2, qf2, d); d = fmaf(x3, qf3, d);        \
    d = fmaf(x4, qf4, d); d = fmaf(x5, qf5, d); d = fmaf(x6, qf6, d);        \
    d = fmaf(x7, qf7, d);                                                    \
    d += __shfl_xor(d, 1);                                                   \
    d += __shfl_xor(d, 2);                                                   \
    float lg = __shfl(d, sub);                                               \
    lg = (valid) ? lg : -INFINITY;                                           \
    if (__any(lg - m > 8.0f)) {                                              \
      float nm = fmaxf(m, lg);                                               \
      float sc = __expf(m - nm);                                             \
      denom *= sc;                                                           \
      a0 *= sc; a1 *= sc; a2 *= sc; a3 *= sc;                                \
      a4 *= sc; a5 *= sc; a6 *= sc; a7 *= sc;                                \
      m = nm;                                                                \
    }                                                                        \
    float p = __expf(lg - m);                                                \
    denom += p;                                                              \
    a0 = fmaf(p, x0, a0); a1 = fmaf(p, x1, a1);                              \
    a2 = fmaf(p, x2, a2); a3 = fmaf(p, x3, a3);                              \
    a4 = fmaf(p, x4, a4); a5 = fmaf(p, x5, a5);                              \
    a6 = fmaf(p, x6, a6); a7 = fmaf(p, x7, a7);                              \
  }

__global__ __launch_bounds__(256) void attn_kernel(
    const __hip_bfloat16* __restrict__ Q, const __hip_bfloat16* __restrict__ KV,
    const int* __restrict__ offsets, const int* __restrict__ col_sorted,
    float* __restrict__ out, int n_node) {
  __shared__ char kvbuf[4][2][4][1024];  // [wave][slot][edge][row]
  int wave = threadIdx.x >> 6;
  int lane = threadIdx.x & 63;
  int sub = lane & 31;
  int node = blockIdx.x * 4 + wave;
  if (node >= n_node) return;
  int start = offsets[node], end = offsets[node + 1];

  const float QS = 0.17677669529663687f;
  float qf0, qf1, qf2, qf3, qf4, qf5, qf6, qf7;
  {
    uint4 qr = *(const uint4*)(Q + (size_t)node * HD + sub * 8);
    qf0 = u2f(qr.x << 16) * QS; qf1 = u2f(qr.x & 0xFFFF0000u) * QS;
    qf2 = u2f(qr.y << 16) * QS; qf3 = u2f(qr.y & 0xFFFF0000u) * QS;
    qf4 = u2f(qr.z << 16) * QS; qf5 = u2f(qr.z & 0xFFFF0000u) * QS;
    qf6 = u2f(qr.w << 16) * QS; qf7 = u2f(qr.w & 0xFFFF0000u) * QS;
  }
  float m = -INFINITY, denom = 0.f;
  float a0 = 0.f, a1 = 0.f, a2 = 0.f, a3 = 0.f;
  float a4 = 0.f, a5 = 0.f, a6 = 0.f, a7 = 0.f;

  char* myb = &kvbuf[wave][0][0][0];

  for (int base = start; base < end; base += 64) {
    int nn = min(64, end - base);
    int myc = col_sorted[base + (lane < nn ? lane : 0)];
    int ng = (nn + 3) >> 2;

    auto issue = [&](int g) {
      char* slotb = myb + (g & 1) * 4096;
      #pragma unroll
      for (int j = 0; j < 4; j++) {
        int idx = g * 4 + j;
        int c = __shfl(myc, idx < nn ? idx : 0, 64);
        const char* src = (const char*)KV + (size_t)c * 1024 + lane * 16;
        gll16(src, slotb + j * 1024);
      }
    };

    issue(0);
    if (ng > 1) issue(1);

    for (int g = 0; g < ng; ++g) {
      if (g + 1 < ng) {
        asm volatile("s_waitcnt vmcnt(4)" ::: "memory");
      } else {
        asm volatile("s_waitcnt vmcnt(0)" ::: "memory");
      }
      __builtin_amdgcn_sched_barrier(0);
      const char* slotb = myb + (g & 1) * 4096;
      #pragma unroll
      for (int j = 0; j < 4; j++) {
        uint4 r = *(const uint4*)(slotb + j * 1024 + lane * 16);
        bool valid = (g * 4 + j) < nn;
        AT_PROCESS(r, valid);
      }
      __builtin_amdgcn_sched_barrier(0);
      if (g + 2 < ng) issue(g + 2);
    }
  }

  float inv = (end > start) ? 1.f / denom : 0.f;
  if (lane >= 32) {
    float* op = out + (size_t)node * HD + sub * 8;
    float4 o0 = make_float4(a0 * inv, a1 * inv, a2 * inv, a3 * inv);
    float4 o1 = make_float4(a4 * inv, a5 * inv, a6 * inv, a7 * inv);
    *(float4*)op = o0;
    *(float4*)(op + 4) = o1;
  }
}

extern "C" void kernel_launch(void* const* d_in, const int* in_sizes, int n_in,
                              void* d_out, int out_size, void* d_ws,
                              size_t ws_size, hipStream_t stream) {
  const float* h = (const float*)d_in[0];
  const int* edge = (const int*)d_in[1];
  const float* WQ = (const float*)d_in[2];
  const float* WK = (const float*)d_in[3];
  const float* WV = (const float*)d_in[4];
  float* out = (float*)d_out;

  int n_node = in_sizes[0] / D_IN;
  int n_edge = in_sizes[1] / 2;
  const int* row = edge;
  const int* col = edge + n_edge;

  char* ws = (char*)d_ws;
  size_t off = 0;
  auto alloc = [&](size_t bytes) {
    void* p = ws + off;
    off += (bytes + 255) & ~(size_t)255;
    return p;
  };
  int nt_total = (n_node + 15) / 16;  // 3125 (50000 = 3125*16 exactly)
  __hip_bfloat16* Q = (__hip_bfloat16*)alloc((size_t)nt_total * 16 * HD * 2);
  __hip_bfloat16* KV = (__hip_bfloat16*)alloc((size_t)nt_total * 16 * KVW * 2);
  short8* Bbuf = (short8*)alloc((size_t)48 * 4 * 64 * 16);
  int* col_sorted = (int*)alloc((size_t)n_edge * 4);
  int* rank = (int*)alloc((size_t)n_edge * 4);
  int* cnt = (int*)alloc((size_t)n_node * 4);
  int* offsets = (int*)alloc((size_t)(n_node + 1) * 4);
  int* bsum = (int*)alloc(256 * 4);

  hipMemsetAsync(cnt, 0, (size_t)n_node * 4, stream);

  prep_w_kernel<<<48, 256, 0, stream>>>(WQ, WK, WV, Bbuf);
  gemm_qkv_kernel<<<nt_total, 256, 0, stream>>>(h, Bbuf, Q, KV, nt_total);

  int nb_e = (n_edge + 255) / 256;
  rank_kernel<<<nb_e, 256, 0, stream>>>(row, n_edge, cnt, rank);

  int nb = (n_node + 255) / 256;
  scan1_kernel<<<nb, 256, 0, stream>>>(cnt, n_node, offsets, bsum);
  scan2_kernel<<<1, 256, 0, stream>>>(bsum, nb);
  scan3_kernel<<<nb, 256, 0, stream>>>(offsets, bsum, n_node, n_edge);

  scatter_kernel<<<nb_e, 256, 0, stream>>>(row, col, rank, n_edge, offsets,
                                           col_sorted);

  attn_kernel<<<(n_node + 3) / 4, 256, 0, stream>>>(Q, KV, offsets, col_sorted,
                                                    out, n_node);
}